// Round 1
// baseline (217.258 us; speedup 1.0000x reference)
//
#include <hip/hip_runtime.h>

// Problem constants
#define BB   8
#define CC   128
#define CR   16      // reduced channels = 128/8
#define HH   128
#define WW   128
#define HWSZ 16384   // 128*128
#define K2   9

// ws layout (floats):
//   t      : [0, 2097152)                 (b, cr, h, w)
//   part   : [2097152, 2097152+16384)     512 blocks x 16 ch x {sum,sumsq}
//   stats  : next 256                     (b, cr) x {scale, shift}

__global__ __launch_bounds__(256) void k_conv1(const float* __restrict__ x,
                                               const float* __restrict__ w1,
                                               float* __restrict__ t,
                                               float* __restrict__ part) {
    const int tile = blockIdx.x;   // 0..63
    const int b    = blockIdx.y;   // 0..7
    const int tid  = threadIdx.x;
    const int pix  = tile * 256 + tid;

    __shared__ float w1s[CR * CC];   // 8 KB
    for (int i = tid; i < CR * CC; i += 256) w1s[i] = w1[i];
    __syncthreads();

    const float* xb = x + (size_t)b * CC * HWSZ + pix;
    float acc[CR];
#pragma unroll
    for (int o = 0; o < CR; ++o) acc[o] = 0.f;

    for (int cin = 0; cin < CC; ++cin) {
        float xv = xb[(size_t)cin * HWSZ];
#pragma unroll
        for (int o = 0; o < CR; ++o)
            acc[o] = fmaf(w1s[o * CC + cin], xv, acc[o]);
    }

    float* tb = t + (size_t)b * CR * HWSZ + pix;
#pragma unroll
    for (int o = 0; o < CR; ++o) tb[(size_t)o * HWSZ] = acc[o];

    // block-level sum / sumsq per reduced channel (deterministic, no atomics)
    __shared__ float red[4][CR][2];
    const int lane = tid & 63;
    const int wv   = tid >> 6;
#pragma unroll
    for (int o = 0; o < CR; ++o) {
        float s = acc[o];
        float q = s * s;
#pragma unroll
        for (int off = 32; off > 0; off >>= 1) {
            s += __shfl_down(s, off, 64);
            q += __shfl_down(q, off, 64);
        }
        if (lane == 0) { red[wv][o][0] = s; red[wv][o][1] = q; }
    }
    __syncthreads();
    if (tid < CR) {
        const int o = tid;
        float s = red[0][o][0] + red[1][o][0] + red[2][o][0] + red[3][o][0];
        float q = red[0][o][1] + red[1][o][1] + red[2][o][1] + red[3][o][1];
        const int blk = b * 64 + tile;
        part[blk * 32 + o * 2 + 0] = s;
        part[blk * 32 + o * 2 + 1] = q;
    }
}

__global__ void k_stats(const float* __restrict__ part,
                        const float* __restrict__ gamma,
                        const float* __restrict__ beta,
                        float* __restrict__ stats) {
    const int tid = threadIdx.x;           // 0..127
    if (tid >= BB * CR) return;
    const int b = tid / CR, o = tid % CR;
    float s = 0.f, q = 0.f;
    for (int tle = 0; tle < 64; ++tle) {
        const int blk = b * 64 + tle;
        s += part[blk * 32 + o * 2 + 0];
        q += part[blk * 32 + o * 2 + 1];
    }
    const float mean = s * (1.f / (float)HWSZ);
    const float var  = q * (1.f / (float)HWSZ) - mean * mean;
    const float rstd = rsqrtf(var + 1e-5f);
    const float sc   = gamma[o] * rstd;
    const float sh   = beta[o] - mean * sc;
    stats[tid * 2 + 0] = sc;
    stats[tid * 2 + 1] = sh;
}

// Fused: weight-gen (w2 @ tn + b2) + dilated 3x3 involution apply.
// block = 128(x) x 2(y rows); each thread: 1 pixel x 16 channels.
// grid  = (64 ytiles, 8 batches, 8 channel-groups)
__global__ __launch_bounds__(256) void k_main(const float* __restrict__ x,
                                              const float* __restrict__ t,
                                              const float* __restrict__ stats,
                                              const float* __restrict__ w2,
                                              const float* __restrict__ b2,
                                              float* __restrict__ out) {
    const int xpos = threadIdx.x;                    // 0..127
    const int y    = blockIdx.x * 2 + threadIdx.y;   // 0..127
    const int b    = blockIdx.y;
    const int ch0  = blockIdx.z * 16;                // channel group base

    // tn = relu(t * scale + shift), 16 values per pixel, kept in VGPRs
    float tn[CR];
    {
        const float* tb = t + (size_t)b * CR * HWSZ + y * WW + xpos;
        const float* st = stats + b * CR * 2;
#pragma unroll
        for (int r = 0; r < CR; ++r) {
            float v = fmaf(tb[(size_t)r * HWSZ], st[r * 2], st[r * 2 + 1]);
            tn[r] = v > 0.f ? v : 0.f;
        }
    }

    const float* xb = x + ((size_t)b * CC + ch0) * HWSZ;
    float* ob = out + ((size_t)b * CC + ch0) * HWSZ + y * WW + xpos;

#pragma unroll 1
    for (int cc = 0; cc < 16; ++cc) {
        const int c = ch0 + cc;
        // w2 rows for this channel: 144 contiguous floats; address depends
        // only on blockIdx.z + loop constant -> wave-uniform -> scalar loads
        const float* w2r = w2 + (size_t)c * (K2 * CR);
        const float* b2r = b2 + (size_t)c * K2;

        float acc = 0.f;
#pragma unroll
        for (int k = 0; k < K2; ++k) {
            const int dy = (k / 3) * 2 - 2;
            const int dx = (k % 3) * 2 - 2;
            float wv = b2r[k];
#pragma unroll
            for (int r = 0; r < CR; ++r)
                wv = fmaf(w2r[k * CR + r], tn[r], wv);

            const int yy = y + dy;
            const int xx = xpos + dx;
            float pv = 0.f;
            if (yy >= 0 && yy < HH && xx >= 0 && xx < WW)
                pv = xb[(size_t)cc * HWSZ + yy * WW + xx];
            acc = fmaf(wv, pv, acc);
        }
        ob[(size_t)cc * HWSZ] = acc;
    }
}

extern "C" void kernel_launch(void* const* d_in, const int* in_sizes, int n_in,
                              void* d_out, int out_size, void* d_ws, size_t ws_size,
                              hipStream_t stream) {
    const float* x     = (const float*)d_in[0];
    const float* w1    = (const float*)d_in[1];
    const float* gamma = (const float*)d_in[2];
    const float* beta  = (const float*)d_in[3];
    const float* w2    = (const float*)d_in[4];
    const float* b2    = (const float*)d_in[5];
    float* out = (float*)d_out;

    float* ws    = (float*)d_ws;
    float* t     = ws;                       // 2,097,152 floats
    float* part  = ws + 2097152;             // 16,384 floats
    float* stats = part + 16384;             // 256 floats

    dim3 gA(64, 8);
    k_conv1<<<gA, 256, 0, stream>>>(x, w1, t, part);

    k_stats<<<1, 128, 0, stream>>>(part, gamma, beta, stats);

    dim3 gC(64, 8, 8);
    dim3 bC(128, 2);
    k_main<<<gC, bC, 0, stream>>>(x, t, stats, w2, b2, out);
}